// Round 9
// baseline (109.598 us; speedup 1.0000x reference)
//
#include <hip/hip_runtime.h>
#include <math.h>

#define H_DIM 1024
#define N_DIM 64
#define BH 16          // h per block
#define BL 128         // l per segment
#define KL 8           // l per thread (stride 16)
#define NB 16          // n per batch
#define NBATCH (N_DIM / NB)   // 4
#define LPB 2          // l-segments per block
#define REPS 5         // measurement round: repeat identical compute 5x

__device__ __forceinline__ float2 cmul(float2 a, float2 b) {
    return make_float2(fmaf(a.x, b.x, -(a.y * b.y)),
                       fmaf(a.x, b.y,   a.y * b.x));
}

// ---------------- fused: params in registers, pair-vectorized LDS table ----------------
// MEASUREMENT BUILD: body repeated REPS times (identical output each rep) so the
// dispatch exceeds the 40us poison-fills and shows up in rocprof with counters.

__global__ __launch_bounds__(256, 2) void dss_fused(
    const float* __restrict__ log_dt,   // (H,2)
    const float* __restrict__ llnr,     // (N,)
    const float* __restrict__ limv,     // (N,)
    const float* __restrict__ W,        // (H,N,2)
    const int*   __restrict__ Lp,
    float* __restrict__ out)            // (L,H)
{
    __shared__ float2 tblp[NB * BH * 16];    // 32 KB
    __shared__ float2 pqs[NB * BH];          // 2 KB

    const int tid = threadIdx.x;
    const int h0  = blockIdx.x * BH;
    const int g   = blockIdx.y;              // l-segment pair index
    const int L   = *Lp;

    const int bh = tid & 15, bn = tid >> 4;  // builder mapping

    // ---- per-thread param build (NBATCH sets), all in registers ----
    const float dt0 = expf(log_dt[2 * (h0 + bh)]);
    const float dt1 = expf(log_dt[2 * (h0 + bh) + 1]);

    float2 sv[NBATCH], pqv[NBATCH], w0base[NBATCH], s128v[NBATCH];
    #pragma unroll
    for (int bt = 0; bt < NBATCH; ++bt) {
        const int n = bt * NB + bn;
        const float lre = -expf(llnr[n]);
        const float lmi = limv[n];
        const float a = dt0 * lre;
        const float b = dt1 * lmi;
        float sb, cb;
        sincosf(b, &sb, &cb);
        const float eA = expf(a);
        const float2 s = make_float2(eA * cb, eA * sb);   // exp(dt_Lambda)
        sv[bt] = s;

        // Wk = Wc * (exp(dtL)-1) * conj(Lam)/max(|Lam|^2, eps^2)
        const float den = fmaxf(lre * lre + lmi * lmi, 1e-14f);
        const float rr = lre / den, ri = -lmi / den;
        const float em1r = s.x - 1.0f, em1i = s.y;
        const float2 wc = ((const float2*)W)[(size_t)(h0 + bh) * N_DIM + n];
        const float tr = em1r * rr - em1i * ri;
        const float ti = em1r * ri + em1i * rr;
        const float2 wk = make_float2(wc.x * tr - wc.y * ti,
                                      wc.x * ti + wc.y * tr);

        const float2 s2 = cmul(s, s), s4 = cmul(s2, s2);
        const float2 s8 = cmul(s4, s4), s16 = cmul(s8, s8);
        pqv[bt] = make_float2(2.0f * s16.x,
                              -(fmaf(s16.x, s16.x, s16.y * s16.y)));
        const float2 s32 = cmul(s16, s16), s64 = cmul(s32, s32);
        const float2 s128 = cmul(s64, s64);
        s128v[bt] = s128;

        // w0 = wk * s^(128 * (LPB*g)) = wk * (s^256)^g   (g <= 7)
        const float2 s256  = cmul(s128, s128);
        const float2 s512  = cmul(s256, s256);
        const float2 s1024 = cmul(s512, s512);
        float2 z = wk;
        if (g & 1) z = cmul(z, s256);
        if (g & 2) z = cmul(z, s512);
        if (g & 4) z = cmul(z, s1024);
        w0base[bt] = z;
    }

    // consumer mapping
    const int h = tid >> 4, sub = tid & 15;
    const int rdoff = sub ^ h;               // swizzled pair position

    #pragma unroll 1
    for (int rep = 0; rep < REPS; ++rep) {
        float2 w0v[NBATCH];
        #pragma unroll
        for (int bt = 0; bt < NBATCH; ++bt) w0v[bt] = w0base[bt];

        #pragma unroll
        for (int ls = 0; ls < LPB; ++ls) {
            const int lseg = g * LPB + ls;
            const int l0 = lseg * BL;
            if (l0 < L) {                        // block-uniform
                float acc[KL];
                #pragma unroll
                for (int k = 0; k < KL; ++k) acc[k] = 0.0f;

                #pragma unroll
                for (int bt = 0; bt < NBATCH; ++bt) {
                    __syncthreads();   // previous phase's readers done before overwrite
                    {   // ---- build: thread owns (bh, n = bt*NB + bn) ----
                        const float2 w0 = w0v[bt], s = sv[bt];
                        const float p1 = 2.0f * s.x;
                        const float q1 = -(fmaf(s.x, s.x, s.y * s.y));
                        float t[32];
                        t[0] = w0.x;                                // Re(wk s^l0)
                        t[1] = fmaf(w0.x, s.x, -(w0.y * s.y));      // Re(wk s^(l0+1))
                        #pragma unroll
                        for (int j = 2; j < 32; ++j)
                            t[j] = fmaf(p1, t[j - 1], q1 * t[j - 2]);

                        float2* row = &tblp[(bn * BH + bh) * 16];
                        #pragma unroll
                        for (int p = 0; p < 16; ++p)
                            row[p ^ bh] = make_float2(t[p], t[p + 16]);  // ds_write_b64
                        pqs[bn * BH + bh] = pqv[bt];   // per-batch staging
                    }
                    __syncthreads();

                    // ---- consume: one ds_read_b64 per n gives (ta, tb) seed ----
                    const float2* rowh = &tblp[h * 16 + rdoff];
                    #pragma unroll
                    for (int nl = 0; nl < NB; ++nl) {
                        const float2 tab = rowh[nl * (BH * 16)];
                        const float2 pq  = pqs[nl * BH + h];
                        float ta = tab.x, tb = tab.y;
                        acc[0] += ta;
                        acc[1] += tb;
                        #pragma unroll
                        for (int k = 2; k < KL; ++k) {
                            const float tc = fmaf(pq.x, tb, pq.y * ta);
                            acc[k] += tc;
                            ta = tb; tb = tc;
                        }
                    }
                }

                // ---- epilogue: LDS transpose -> float4 coalesced stores ----
                __syncthreads();
                float* scr = (float*)tblp;       // [128 l][16 h] floats = 8 KB
                #pragma unroll
                for (int k = 0; k < KL; ++k)
                    scr[(sub + 16 * k) * BH + h] = acc[k];
                __syncthreads();
                const float4* scr4 = (const float4*)scr;
                float4* out4 = (float4*)out;
                #pragma unroll
                for (int i = 0; i < 2; ++i) {
                    const int flat = i * 256 + tid;  // float4 index: 128 l x 4
                    const int ll = flat >> 2, q = flat & 3;
                    const int l = l0 + ll;
                    if (l < L) out4[(size_t)l * (H_DIM / 4) + (h0 >> 2) + q] = scr4[flat];
                }
            }
            // advance start values by s^128 for the next l-segment
            if (ls + 1 < LPB) {
                #pragma unroll
                for (int bt = 0; bt < NBATCH; ++bt)
                    w0v[bt] = cmul(w0v[bt], s128v[bt]);
            }
        }
    }
}

// ---------------- generic fallback (round-1 proven structure) ----------------

#define HT 64
#define CHUNK 16

__global__ __launch_bounds__(256) void dss_kernel_fb(
    const float* __restrict__ log_dt,
    const float* __restrict__ lam_log_neg_re,
    const float* __restrict__ lam_im,
    const float* __restrict__ W,
    const int*   __restrict__ Lp,
    float* __restrict__ out,
    int H, int N)
{
    __shared__ float4 params[N_DIM * HT];
    const int tid = threadIdx.x;
    const int h0 = blockIdx.x * HT;
    const int l0_blk = blockIdx.y * 64;
    const int L = *Lp;
    const float2* __restrict__ W2 = (const float2*)W;

    for (int flat = tid; flat < N * HT; flat += 256) {
        const int hl = flat & (HT - 1);
        const int n  = flat >> 6;
        const int h  = h0 + hl;
        const float dt0 = expf(log_dt[2 * h]);
        const float dt1 = expf(log_dt[2 * h + 1]);
        const float lre = -expf(lam_log_neg_re[n]);
        const float lmi = lam_im[n];
        const float a = dt0 * lre;
        const float b = dt1 * lmi;
        const float eA = expf(a);
        float sb, cb;
        sincosf(b, &sb, &cb);
        const float em1r = eA * cb - 1.0f;
        const float em1i = eA * sb;
        const float den = fmaxf(lre * lre + lmi * lmi, 1e-14f);
        const float rr =  lre / den;
        const float ri = -lmi / den;
        const float2 wc = W2[h * N + n];
        const float trm = em1r * rr - em1i * ri;
        const float tim = em1r * ri + em1i * rr;
        params[flat] = make_float4(a, b,
                                   wc.x * trm - wc.y * tim,
                                   wc.x * tim + wc.y * trm);
    }
    __syncthreads();

    const int hl = tid & (HT - 1);
    const int chunk = tid >> 6;
    const int l0 = l0_blk + chunk * CHUNK;
    if (l0 >= L) return;

    float acc[CHUNK];
    #pragma unroll
    for (int k = 0; k < CHUNK; ++k) acc[k] = 0.0f;

    const double TWO_PI  = 6.283185307179586476925286766559;
    const double INV_2PI = 0.15915494309189533576888376337251;

    for (int n = 0; n < N; ++n) {
        const float4 pp = params[n * HT + hl];
        const float a = pp.x, b = pp.y, wr = pp.z, wi = pp.w;
        double ph = (double)b * (double)l0;
        ph -= TWO_PI * rint(ph * INV_2PI);
        const float th = (float)ph;
        const float e0 = expf(a * (float)l0);
        float s0, c0;
        sincosf(th, &s0, &c0);
        float zr = e0 * c0;
        float zi = e0 * s0;
        const float eA = expf(a);
        float sb, cb;
        sincosf(b, &sb, &cb);
        const float str = eA * cb;
        const float sti = eA * sb;
        #pragma unroll
        for (int k = 0; k < CHUNK; ++k) {
            acc[k] = fmaf(wr, zr, fmaf(-wi, zi, acc[k]));
            const float nzr = zr * str - zi * sti;
            const float nzi = fmaf(zr, sti, zi * str);
            zr = nzr; zi = nzi;
        }
    }

    #pragma unroll
    for (int k = 0; k < CHUNK; ++k) {
        const int l = l0 + k;
        if (l < L) out[(size_t)l * H + h0 + hl] = acc[k];
    }
}

// ---------------- launch ----------------

extern "C" void kernel_launch(void* const* d_in, const int* in_sizes, int n_in,
                              void* d_out, int out_size, void* d_ws, size_t ws_size,
                              hipStream_t stream) {
    const float* log_dt = (const float*)d_in[0];
    const float* llnr   = (const float*)d_in[1];
    const float* lim    = (const float*)d_in[2];
    const float* W      = (const float*)d_in[3];
    const int*   Lp     = (const int*)d_in[4];

    const int H = in_sizes[0] / 2;
    const int N = in_sizes[1];
    const int L = out_size / (H > 0 ? H : 1);

    if (H == H_DIM && N == N_DIM && L <= LPB * 8 * BL) {
        const int lsegs = (L + BL - 1) / BL;
        const int gpairs = (lsegs + LPB - 1) / LPB;
        dim3 grid(H_DIM / BH, gpairs);
        dss_fused<<<grid, 256, 0, stream>>>(log_dt, llnr, lim, W, Lp, (float*)d_out);
    } else {
        dim3 grid((H + HT - 1) / HT, (L + 63) / 64);
        dss_kernel_fb<<<grid, 256, 0, stream>>>(log_dt, llnr, lim, W, Lp,
                                                (float*)d_out, H, N);
    }
}

// Round 10
// 22.384 us; speedup vs baseline: 4.8963x; 4.8963x over previous
//
#include <hip/hip_runtime.h>
#include <math.h>

#define H_DIM 1024
#define N_DIM 64
#define BH 16          // h per block
#define BL 128         // l per block
#define KL 8           // l per thread (stride 16)
#define NB 16          // n per batch
#define NBATCH (N_DIM / NB)   // 4

__device__ __forceinline__ float2 cmul(float2 a, float2 b) {
    return make_float2(fmaf(a.x, b.x, -(a.y * b.y)),
                       fmaf(a.x, b.y,   a.y * b.x));
}

// ---------------- fused: params in registers, pair-vectorized LDS table ----------------
// tblp row (n,h): 16 float2 pairs, pair c at pos (c ^ h): (t(l0+c), t(l0+c+16))
// 1024 blocks = 4 blocks/CU; builder uses two 16-step chains (2-way ILP).

__global__ __launch_bounds__(256, 4) void dss_fused(
    const float* __restrict__ log_dt,   // (H,2)
    const float* __restrict__ llnr,     // (N,)
    const float* __restrict__ limv,     // (N,)
    const float* __restrict__ W,        // (H,N,2)
    const int*   __restrict__ Lp,
    float* __restrict__ out)            // (L,H)
{
    __shared__ float2 tblp[NB * BH * 16];    // 32 KB
    __shared__ float2 pqs[NB * BH];          // 2 KB

    const int tid = threadIdx.x;
    const int h0  = blockIdx.x * BH;
    const int g   = blockIdx.y;              // l-segment index (0..15)
    const int l0  = g * BL;
    const int L   = *Lp;

    const int bh = tid & 15, bn = tid >> 4;  // builder mapping

    // ---- per-thread param build (NBATCH sets), all in registers ----
    const float dt0 = expf(log_dt[2 * (h0 + bh)]);
    const float dt1 = expf(log_dt[2 * (h0 + bh) + 1]);

    float2 sv[NBATCH], s16v[NBATCH], pqv[NBATCH], w0v[NBATCH];
    #pragma unroll
    for (int bt = 0; bt < NBATCH; ++bt) {
        const int n = bt * NB + bn;
        const float lre = -expf(llnr[n]);
        const float lmi = limv[n];
        const float a = dt0 * lre;
        const float b = dt1 * lmi;
        float sb, cb;
        sincosf(b, &sb, &cb);
        const float eA = expf(a);
        const float2 s = make_float2(eA * cb, eA * sb);   // exp(dt_Lambda)
        sv[bt] = s;

        // Wk = Wc * (exp(dtL)-1) * conj(Lam)/max(|Lam|^2, eps^2)
        const float den = fmaxf(lre * lre + lmi * lmi, 1e-14f);
        const float rr = lre / den, ri = -lmi / den;
        const float em1r = s.x - 1.0f, em1i = s.y;
        const float2 wc = ((const float2*)W)[(size_t)(h0 + bh) * N_DIM + n];
        const float tr = em1r * rr - em1i * ri;
        const float ti = em1r * ri + em1i * rr;
        const float2 wk = make_float2(wc.x * tr - wc.y * ti,
                                      wc.x * ti + wc.y * tr);

        const float2 s2 = cmul(s, s), s4 = cmul(s2, s2);
        const float2 s8 = cmul(s4, s4), s16 = cmul(s8, s8);
        s16v[bt] = s16;
        pqv[bt] = make_float2(2.0f * s16.x,
                              -(fmaf(s16.x, s16.x, s16.y * s16.y)));

        // w0 = wk * s^(128*g) = wk * (s^128)^g, g <= 15: 4-bit square-multiply
        const float2 s32 = cmul(s16, s16), s64 = cmul(s32, s32);
        const float2 s128  = cmul(s64, s64);
        const float2 s256  = cmul(s128, s128);
        const float2 s512  = cmul(s256, s256);
        const float2 s1024 = cmul(s512, s512);
        float2 z = wk;
        if (g & 1) z = cmul(z, s128);
        if (g & 2) z = cmul(z, s256);
        if (g & 4) z = cmul(z, s512);
        if (g & 8) z = cmul(z, s1024);
        w0v[bt] = z;
    }

    // consumer mapping
    const int h = tid >> 4, sub = tid & 15;
    const int rdoff = sub ^ h;               // swizzled pair position

    float acc[KL];
    #pragma unroll
    for (int k = 0; k < KL; ++k) acc[k] = 0.0f;

    #pragma unroll
    for (int bt = 0; bt < NBATCH; ++bt) {
        __syncthreads();   // previous phase's readers done before overwrite
        {   // ---- build: dual 16-step chains (2-way ILP), pair written as produced ----
            const float2 w0 = w0v[bt], s = sv[bt];
            const float p1 = 2.0f * s.x;
            const float q1 = -(fmaf(s.x, s.x, s.y * s.y));
            const float2 w16 = cmul(w0, s16v[bt]);       // wk * s^(l0+16)

            float2* row = &tblp[(bn * BH + bh) * 16];
            float pa = w0.x;                              // t(l0)
            float ca = fmaf(w0.x, s.x, -(w0.y * s.y));    // t(l0+1)
            float pb = w16.x;                             // t(l0+16)
            float cb2 = fmaf(w16.x, s.x, -(w16.y * s.y)); // t(l0+17)
            row[0 ^ bh] = make_float2(pa, pb);
            row[1 ^ bh] = make_float2(ca, cb2);
            #pragma unroll
            for (int j = 2; j < 16; ++j) {
                const float na = fmaf(p1, ca, q1 * pa);
                const float nb = fmaf(p1, cb2, q1 * pb);
                row[j ^ bh] = make_float2(na, nb);
                pa = ca; ca = na; pb = cb2; cb2 = nb;
            }
            pqs[bn * BH + bh] = pqv[bt];   // per-batch staging (every batch)
        }
        __syncthreads();

        // ---- consume: one ds_read_b64 per n gives (ta, tb) seed ----
        const float2* rowh = &tblp[h * 16 + rdoff];
        #pragma unroll
        for (int nl = 0; nl < NB; ++nl) {
            const float2 tab = rowh[nl * (BH * 16)];
            const float2 pq  = pqs[nl * BH + h];
            float ta = tab.x, tb = tab.y;
            acc[0] += ta;
            acc[1] += tb;
            #pragma unroll
            for (int k = 2; k < KL; ++k) {
                const float tc = fmaf(pq.x, tb, pq.y * ta);
                acc[k] += tc;
                ta = tb; tb = tc;
            }
        }
    }

    // ---- epilogue: LDS transpose -> float4 coalesced stores ----
    __syncthreads();
    float* scr = (float*)tblp;               // [128 l][16 h] floats = 8 KB
    #pragma unroll
    for (int k = 0; k < KL; ++k)
        scr[(sub + 16 * k) * BH + h] = acc[k];
    __syncthreads();
    const float4* scr4 = (const float4*)scr;
    float4* out4 = (float4*)out;
    #pragma unroll
    for (int i = 0; i < 2; ++i) {
        const int flat = i * 256 + tid;      // float4 index: 128 l x 4
        const int ll = flat >> 2, q = flat & 3;
        const int l = l0 + ll;
        if (l < L) out4[(size_t)l * (H_DIM / 4) + (h0 >> 2) + q] = scr4[flat];
    }
}

// ---------------- generic fallback (round-1 proven structure) ----------------

#define HT 64
#define CHUNK 16

__global__ __launch_bounds__(256) void dss_kernel_fb(
    const float* __restrict__ log_dt,
    const float* __restrict__ lam_log_neg_re,
    const float* __restrict__ lam_im,
    const float* __restrict__ W,
    const int*   __restrict__ Lp,
    float* __restrict__ out,
    int H, int N)
{
    __shared__ float4 params[N_DIM * HT];
    const int tid = threadIdx.x;
    const int h0 = blockIdx.x * HT;
    const int l0_blk = blockIdx.y * 64;
    const int L = *Lp;
    const float2* __restrict__ W2 = (const float2*)W;

    for (int flat = tid; flat < N * HT; flat += 256) {
        const int hl = flat & (HT - 1);
        const int n  = flat >> 6;
        const int h  = h0 + hl;
        const float dt0 = expf(log_dt[2 * h]);
        const float dt1 = expf(log_dt[2 * h + 1]);
        const float lre = -expf(lam_log_neg_re[n]);
        const float lmi = lam_im[n];
        const float a = dt0 * lre;
        const float b = dt1 * lmi;
        const float eA = expf(a);
        float sb, cb;
        sincosf(b, &sb, &cb);
        const float em1r = eA * cb - 1.0f;
        const float em1i = eA * sb;
        const float den = fmaxf(lre * lre + lmi * lmi, 1e-14f);
        const float rr =  lre / den;
        const float ri = -lmi / den;
        const float2 wc = W2[h * N + n];
        const float trm = em1r * rr - em1i * ri;
        const float tim = em1r * ri + em1i * rr;
        params[flat] = make_float4(a, b,
                                   wc.x * trm - wc.y * tim,
                                   wc.x * tim + wc.y * trm);
    }
    __syncthreads();

    const int hl = tid & (HT - 1);
    const int chunk = tid >> 6;
    const int l0 = l0_blk + chunk * CHUNK;
    if (l0 >= L) return;

    float acc[CHUNK];
    #pragma unroll
    for (int k = 0; k < CHUNK; ++k) acc[k] = 0.0f;

    const double TWO_PI  = 6.283185307179586476925286766559;
    const double INV_2PI = 0.15915494309189533576888376337251;

    for (int n = 0; n < N; ++n) {
        const float4 pp = params[n * HT + hl];
        const float a = pp.x, b = pp.y, wr = pp.z, wi = pp.w;
        double ph = (double)b * (double)l0;
        ph -= TWO_PI * rint(ph * INV_2PI);
        const float th = (float)ph;
        const float e0 = expf(a * (float)l0);
        float s0, c0;
        sincosf(th, &s0, &c0);
        float zr = e0 * c0;
        float zi = e0 * s0;
        const float eA = expf(a);
        float sb, cb;
        sincosf(b, &sb, &cb);
        const float str = eA * cb;
        const float sti = eA * sb;
        #pragma unroll
        for (int k = 0; k < CHUNK; ++k) {
            acc[k] = fmaf(wr, zr, fmaf(-wi, zi, acc[k]));
            const float nzr = zr * str - zi * sti;
            const float nzi = fmaf(zr, sti, zi * str);
            zr = nzr; zi = nzi;
        }
    }

    #pragma unroll
    for (int k = 0; k < CHUNK; ++k) {
        const int l = l0 + k;
        if (l < L) out[(size_t)l * H + h0 + hl] = acc[k];
    }
}

// ---------------- launch ----------------

extern "C" void kernel_launch(void* const* d_in, const int* in_sizes, int n_in,
                              void* d_out, int out_size, void* d_ws, size_t ws_size,
                              hipStream_t stream) {
    const float* log_dt = (const float*)d_in[0];
    const float* llnr   = (const float*)d_in[1];
    const float* lim    = (const float*)d_in[2];
    const float* W      = (const float*)d_in[3];
    const int*   Lp     = (const int*)d_in[4];

    const int H = in_sizes[0] / 2;
    const int N = in_sizes[1];
    const int L = out_size / (H > 0 ? H : 1);

    if (H == H_DIM && N == N_DIM && L <= 16 * BL) {
        const int lsegs = (L + BL - 1) / BL;
        dim3 grid(H_DIM / BH, lsegs);      // 64 x 16 = 1024 blocks = 4/CU
        dss_fused<<<grid, 256, 0, stream>>>(log_dt, llnr, lim, W, Lp, (float*)d_out);
    } else {
        dim3 grid((H + HT - 1) / HT, (L + 63) / 64);
        dss_kernel_fb<<<grid, 256, 0, stream>>>(log_dt, llnr, lim, W, Lp,
                                                (float*)d_out, H, N);
    }
}